// Round 5
// baseline (269.928 us; speedup 1.0000x reference)
//
#include <hip/hip_runtime.h>

typedef _Float16 f16;
typedef unsigned int uint;
typedef f16 f16x2 __attribute__((ext_vector_type(2)));
typedef f16 f16x8 __attribute__((ext_vector_type(8)));
typedef __fp16 h16x2 __attribute__((ext_vector_type(2)));
typedef float f32x4 __attribute__((ext_vector_type(4)));

#define Bn 512
#define Ln 128
#define Dn 128
#define Cn 512   // 4 gates * D

__device__ __forceinline__ float fdot2f(uint a, uint b, float c) {
#if __has_builtin(__builtin_amdgcn_fdot2)
  return __builtin_amdgcn_fdot2(__builtin_bit_cast(f16x2, a),
                                __builtin_bit_cast(f16x2, b), c, false);
#else
  f16x2 av = __builtin_bit_cast(f16x2, a), bv = __builtin_bit_cast(f16x2, b);
  return c + (float)av[0] * (float)bv[0] + (float)av[1] * (float)bv[1];
#endif
}

__device__ __forceinline__ uint pk2(float a, float b) {
#if __has_builtin(__builtin_amdgcn_cvt_pkrtz)
  h16x2 v = __builtin_amdgcn_cvt_pkrtz(a, b);
  return __builtin_bit_cast(uint, v);
#else
  f16x2 v; v[0] = (f16)a; v[1] = (f16)b;
  return __builtin_bit_cast(uint, v);
#endif
}

// DPP row_ror<N> (VALU, 2-cyc): rotational reduce within 16-lane rows.
template<int CTRL>
__device__ __forceinline__ float rorf(float x) {
#if __has_builtin(__builtin_amdgcn_mov_dpp)
  int r = __builtin_amdgcn_mov_dpp(__builtin_bit_cast(int, x), CTRL, 0xF, 0xF, true);
  return __builtin_bit_cast(float, r);
#else
  return __shfl_xor(x, (CTRL - 0x120));
#endif
}

// lane ^ 16 exchange via ds_swizzle (BitMode xor=16, and=0x1F) — LDS pipe,
// result intentionally NOT consumed at issue site (deferred to next step).
__device__ __forceinline__ int swz16i(float x) {
#if __has_builtin(__builtin_amdgcn_ds_swizzle)
  return __builtin_amdgcn_ds_swizzle(__builtin_bit_cast(int, x), 0x401F);
#else
  return __builtin_bit_cast(int, __shfl_xor(x, 16));
#endif
}

__device__ __forceinline__ void read_hu(const f16* base, uint hu[16]) {
  const uint4* hq = (const uint4*)base;
  uint4 q0 = hq[0], q1 = hq[1], q2 = hq[2], q3 = hq[3];
  hu[0]=q0.x; hu[1]=q0.y; hu[2]=q0.z; hu[3]=q0.w;
  hu[4]=q1.x; hu[5]=q1.y; hu[6]=q1.z; hu[7]=q1.w;
  hu[8]=q2.x; hu[9]=q2.y; hu[10]=q2.z; hu[11]=q2.w;
  hu[12]=q3.x; hu[13]=q3.y; hu[14]=q3.z; hu[15]=q3.w;
}

// ---------------- convert: W -> MFMA-fragment-ordered f16 (WhF), R -> transposed f16 ----------------
__global__ __launch_bounds__(256) void k_convert(const float* __restrict__ Wg,
                                                 const float* __restrict__ Rg,
                                                 f16* __restrict__ WhF,
                                                 f16* __restrict__ RT) {
  int i = blockIdx.x * 256 + threadIdx.x;
  const int nWfrag = 2 * 4 * 32 * 64;   // 16384 groups of 8 f16
  if (i < nWfrag) {
    int lane = i & 63;
    int ii   = (i >> 6) & 31;
    int kk   = (i >> 11) & 3;
    int l    = i >> 13;
    int c = ii * 16 + (lane & 15);
    int d = kk * 32 + ((lane >> 4) << 3);
    const float* src = Wg + ((size_t)(l * 512 + c) * 128 + d);
    f16* dst = WhF + (size_t)i * 8;
    #pragma unroll
    for (int j = 0; j < 8; ++j) dst[j] = (f16)src[j];
  } else {
    int j = i - nWfrag;  // 32768 = 2*4*4*32*32
    if (j < 32768) {
      int dd = j & 31;
      int e  = (j >> 5) & 31;
      int hh = (j >> 10) & 3;
      int g  = (j >> 12) & 3;
      int l  = j >> 14;
      RT[j] = (f16)Rg[((((l * 4 + g) * 4 + hh) * 32 + dd) * 32) + e];
    }
  }
}

// ---------------- GEMM with inline LayerNorm (and optional embedding gather) ----------------
// EMB=1: row source = emb[ids[row]]; EMB=0: row source = xsrc[row].
// Row LN stats: 32 f32/lane partial sums + 2 wave shuffles (lanes sharing l16).
template<int EMB>
__global__ __launch_bounds__(256) void k_gemm(const float* __restrict__ xsrc,
                                              const int* __restrict__ ids,
                                              const float* __restrict__ lw,
                                              const float* __restrict__ lb,
                                              const f16* __restrict__ WhF,
                                              const float* __restrict__ bias,
                                              uint2* __restrict__ preP) {
  int w = threadIdx.x >> 6;
  int lane = threadIdx.x & 63;
  int l16 = lane & 15, quad = lane >> 4;
  int m0 = blockIdx.x * 64 + w * 16;

  const float* src;
  if (EMB) src = xsrc + (size_t)ids[m0 + l16] * Dn;
  else     src = xsrc + (size_t)(m0 + l16) * Dn;
  const float* sp = src + quad * 8;

  // load this lane's 32 f32 (dims kk*32 + quad*8 + 0..7)
  f32x4 v[4][2];
  #pragma unroll
  for (int kk = 0; kk < 4; ++kk) {
    v[kk][0] = *(const f32x4*)(sp + kk * 32);
    v[kk][1] = *(const f32x4*)(sp + kk * 32 + 4);
  }
  // row stats: in-lane partial + butterfly over quad groups
  float s1 = 0.f, s2 = 0.f;
  #pragma unroll
  for (int kk = 0; kk < 4; ++kk)
    #pragma unroll
    for (int p = 0; p < 2; ++p)
      #pragma unroll
      for (int j = 0; j < 4; ++j) {
        float vv = v[kk][p][j];
        s1 += vv; s2 = fmaf(vv, vv, s2);
      }
  s1 += __shfl_xor(s1, 16);  s2 += __shfl_xor(s2, 16);
  s1 += __shfl_xor(s1, 32);  s2 += __shfl_xor(s2, 32);
  float mu = s1 * (1.f / 128.f);
  float var = s2 * (1.f / 128.f) - mu * mu;
  float rs = rsqrtf(var + 1e-5f);

  // normalize -> f16 fragments
  f16x8 a[4];
  #pragma unroll
  for (int kk = 0; kk < 4; ++kk) {
    #pragma unroll
    for (int p = 0; p < 2; ++p) {
      int d0 = kk * 32 + quad * 8 + p * 4;
      f32x4 lw4 = *(const f32x4*)(lw + d0);
      f32x4 lb4 = *(const f32x4*)(lb + d0);
      #pragma unroll
      for (int j = 0; j < 4; ++j)
        a[kk][p * 4 + j] = (f16)((v[kk][p][j] - mu) * rs * lw4[j] + lb4[j]);
    }
  }

  float bv[32];
  #pragma unroll
  for (int i = 0; i < 32; ++i) bv[i] = bias[i * 16 + l16];

  f32x4 acc[32] = {};
  const f16* bbase = WhF + (size_t)lane * 8;
  #pragma unroll
  for (int kk = 0; kk < 4; ++kk) {
    #pragma unroll
    for (int i = 0; i < 32; ++i) {
      f16x8 bf = *(const f16x8*)(bbase + (size_t)(kk * 32 + i) * 512);
      acc[i] = __builtin_amdgcn_mfma_f32_16x16x32_f16(a[kk], bf, acc[i], 0, 0, 0);
    }
  }
  #pragma unroll
  for (int r = 0; r < 4; ++r) {
    int m = m0 + quad * 4 + r;
    #pragma unroll
    for (int i7 = 0; i7 < 8; ++i7) {
      uint2 vv;
      vv.x = pk2(acc[i7][r]      + bv[i7],      acc[i7 + 8][r]  + bv[i7 + 8]);
      vv.y = pk2(acc[i7 + 16][r] + bv[i7 + 16], acc[i7 + 24][r] + bv[i7 + 24]);
      preP[(size_t)m * Dn + i7 * 16 + l16] = vv;
    }
  }
}

// ---------------- fused scan (r4 pipelined schedule, unchanged math) ----------------
// LAST=0 (layer 0): residual x gathered directly from emb[ids[t]] per step
//                   (wave-uniform row, id pipeline 8 deep, row pipeline 4 deep);
//                   writes xout = x1.
// LAST=1 (layer 1): residual from x1; mean-pool accumulated in-register; head
//                   MLP (128->64 relu ->2) computed in the epilogue via LDS.
template<int LAST>
__global__ __launch_bounds__(256, 1) void k_scan(const uint2* __restrict__ preP,
                                                 const f16* __restrict__ RT,
                                                 const float* __restrict__ gnw,
                                                 const float* __restrict__ xsrc,
                                                 const int* __restrict__ ids,
                                                 float* __restrict__ xout,
                                                 const float* __restrict__ hw1,
                                                 const float* __restrict__ hb1,
                                                 const float* __restrict__ hw2,
                                                 const float* __restrict__ hb2,
                                                 float* __restrict__ out) {
  const int w = threadIdx.x >> 6;       // wave 0..3
  const int lane = threadIdx.x & 63;
  const int s = w >> 1;                 // seq within block
  const int b = blockIdx.x * 2 + s;
  const int d = ((w & 1) << 6) + lane;  // element 0..127 of this seq
  const int head = d >> 5;
  const int e = d & 31;
  const int half = lane >> 5;

  __shared__ __align__(16) f16 hsh[4][64];   // per-wave h exchange
  __shared__ float pool2[2][128];            // LAST: pooled rows
  __shared__ float hid2[2][64];              // LAST: hidden layer

  uint rr[4][16];
  const uint* RT32 = (const uint*)RT;
  #pragma unroll
  for (int g = 0; g < 4; ++g) {
    const uint* p = RT32 + ((g * 4 + head) * 32 + e) * 16;
    #pragma unroll
    for (int j = 0; j < 16; ++j) rr[g][j] = p[j];
  }
  const float gw = gnw[d];
  const f16* hbase = &hsh[w][half * 32];   // my head-group's 32 h values

  hsh[w][lane] = (f16)0.f;   // wave-local, DS in-order

  const uint2* pp = preP + (size_t)b * Ln * Dn + d;   // + t*Dn
  const float* xp = xsrc + (size_t)b * Ln * Dn + d;   // LAST=1 residual path
  const int*   idr = ids + b * Ln;                    // LAST=0 gather path
  float* xo = xout + (size_t)b * Ln * Dn + d;

  // 4-deep prefetch pipeline (preP overrun stays inside workspace)
  uint2 pb[4]; float xb[4]; int idb[4];
  #pragma unroll
  for (int k = 0; k < 4; ++k) {
    pb[k] = pp[(size_t)k * Dn];
    if (LAST) {
      xb[k] = xp[(size_t)k * Dn];
    } else {
      xb[k] = xsrc[(size_t)idr[k] * Dn + d];
      idb[k] = idr[k + 4];
    }
  }

  // preheader: hu for t=0 (all zeros, but read keeps the pipeline uniform)
  uint hu[16];
  read_hu(hbase, hu);

  float cc = 0.f, nc = 0.f, mc = 0.f, psum = 0.f;
  float hprev = 0.f, xprev = 0.f;
  float u1 = 0.f, u2 = 0.f;   // 16-row partial GN sums of step t-1
  int   w1 = 0,   w2 = 0;     // raw ds_swizzle results (other 16-row sums)

  #pragma unroll 1
  for (int t = 0; t < Ln; t += 4) {
    #pragma unroll
    for (int k = 0; k < 4; ++k) {
      int tt = t + k;
      uint2 pc = pb[k]; float xc = xb[k];
      pb[k] = pp[(size_t)(tt + 4) * Dn];
      if (LAST) {
        xb[k] = xp[(size_t)(tt + 4) * Dn];
      } else {
        xb[k] = xsrc[(size_t)idb[k] * Dn + d];
        int ni = tt + 8;
        idb[k] = idr[ni > 127 ? 127 : ni];
      }

      // GN of step tt-1: combine deferred swizzle halves here
      if (tt > 0) {
        float s1 = u1 + __builtin_bit_cast(float, w1);
        float s2 = u2 + __builtin_bit_cast(float, w2);
        float mu = s1 * (1.f / 32.f);
        float va = s2 * (1.f / 32.f) - mu * mu;
        float ov = xprev + (hprev - mu) * rsqrtf(va + 1e-5f) * gw;
        if (LAST) psum += ov;
        else      xo[(size_t)(tt - 1) * Dn] = ov;
      }

      // recurrence dot products: 8 chains of 8 (2-way split per gate)
      float a0 = 0.f, a1 = 0.f, a2 = 0.f, a3 = 0.f;
      float c0 = 0.f, c1 = 0.f, c2 = 0.f, c3 = 0.f;
      #pragma unroll
      for (int j = 0; j < 8; ++j) {
        a0 = fdot2f(hu[j], rr[0][j], a0);
        a1 = fdot2f(hu[j], rr[1][j], a1);
        a2 = fdot2f(hu[j], rr[2][j], a2);
        a3 = fdot2f(hu[j], rr[3][j], a3);
        c0 = fdot2f(hu[j + 8], rr[0][j + 8], c0);
        c1 = fdot2f(hu[j + 8], rr[1][j + 8], c1);
        c2 = fdot2f(hu[j + 8], rr[2][j + 8], c2);
        c3 = fdot2f(hu[j + 8], rr[3][j + 8], c3);
      }
      f16x2 lo = __builtin_bit_cast(f16x2, pc.x);
      f16x2 hi = __builtin_bit_cast(f16x2, pc.y);
      float it = ((float)lo[0] + a0) + c0;
      float ft = ((float)lo[1] + a1) + c1;
      float zt = ((float)hi[0] + a2) + c2;
      float ot = ((float)hi[1] + a3) + c3;

      float mn = fmaxf(ft + mc, it);
      float iv = __expf(it - mn);
      float fv = __expf(ft + mc - mn);
      float zc = fminf(fmaxf(zt, -15.f), 15.f);
      float ez = __expf(2.f * zc);
      float tz = (ez - 1.f) * __builtin_amdgcn_rcpf(ez + 1.f);
      float cn = fv * cc + iv * tz;
      float nn = fv * nc + iv;
      // h = sigmoid(ot) * c / n = c / ((1 + exp(-ot)) * n)  — single rcp
      float hn = cn * __builtin_amdgcn_rcpf((1.f + __expf(-ot)) * nn);
      cc = cn; nc = nn; mc = mn;

      // --- DS schedule for next step (issue-only, no consumption here) ---
      hsh[w][lane] = (f16)hn;                       // DS op 1: h exchange

      float t1v = hn, t2v = hn * hn;                // VALU rors: 16-row sums
      t1v += rorf<0x121>(t1v);  t2v += rorf<0x121>(t2v);   // ror 1
      t1v += rorf<0x122>(t1v);  t2v += rorf<0x122>(t2v);   // ror 2
      t1v += rorf<0x124>(t1v);  t2v += rorf<0x124>(t2v);   // ror 4
      t1v += rorf<0x128>(t1v);  t2v += rorf<0x128>(t2v);   // ror 8
      w1 = swz16i(t1v);                             // DS ops 2,3: xor-16
      w2 = swz16i(t2v);                             //   (combined next step)
      u1 = t1v; u2 = t2v;

      read_hu(hbase, hu);                           // DS ops 4..7: hu for t+1

      hprev = hn; xprev = xc;
    }
  }

  // epilogue: groupnorm of step 127
  {
    float s1 = u1 + __builtin_bit_cast(float, w1);
    float s2 = u2 + __builtin_bit_cast(float, w2);
    float mu = s1 * (1.f / 32.f);
    float va = s2 * (1.f / 32.f) - mu * mu;
    float ov = xprev + (hprev - mu) * rsqrtf(va + 1e-5f) * gw;
    if (LAST) {
      psum += ov;
      pool2[s][d] = psum * (1.f / 128.f);
      __syncthreads();
      // head MLP: waves 0,2 handle local seqs 0,1
      if ((w & 1) == 0) {
        int sq = w >> 1;
        float acc = hb1[lane];
        const float* wr = hw1 + (size_t)lane * Dn;
        const float* pl = &pool2[sq][0];
        #pragma unroll 8
        for (int dd = 0; dd < Dn; dd += 4) {
          f32x4 wv = *(const f32x4*)(wr + dd);
          acc += wv[0]*pl[dd] + wv[1]*pl[dd+1] + wv[2]*pl[dd+2] + wv[3]*pl[dd+3];
        }
        hid2[sq][lane] = fmaxf(acc, 0.f);
      }
      __syncthreads();
      if ((w & 1) == 0 && lane < 2) {
        int sq = w >> 1;
        float acc = hb2[lane];
        const float* wr = hw2 + lane * 64;
        #pragma unroll 4
        for (int j = 0; j < 64; ++j) acc += hid2[sq][j] * wr[j];
        out[(blockIdx.x * 2 + sq) * 2 + lane] = acc;
      }
    } else {
      xo[(size_t)(Ln - 1) * Dn] = ov;
    }
  }
}

extern "C" void kernel_launch(void* const* d_in, const int* in_sizes, int n_in,
                              void* d_out, int out_size, void* d_ws, size_t ws_size,
                              hipStream_t stream) {
  const int*   ids  = (const int*)d_in[0];
  const float* emb  = (const float*)d_in[1];
  const float* ln_w = (const float*)d_in[2];
  const float* ln_b = (const float*)d_in[3];
  const float* Wg   = (const float*)d_in[4];
  const float* Rg   = (const float*)d_in[5];
  const float* bg   = (const float*)d_in[6];
  const float* gn_w = (const float*)d_in[7];
  const float* w1   = (const float*)d_in[8];
  const float* b1   = (const float*)d_in[9];
  const float* w2   = (const float*)d_in[10];
  const float* b2   = (const float*)d_in[11];
  float* out = (float*)d_out;

  char* ws = (char*)d_ws;
  uint2* preP = (uint2*)ws;                        // 67,108,864 B
  float* x1   = (float*)(ws + 67108864);           // 33,554,432 B
  f16*   WhF  = (f16*)(ws + 100663296);            //    262,144 B
  f16*   RT   = (f16*)(ws + 100663296 + 262144);   //     65,536 B

  k_convert<<<192, 256, 0, stream>>>(Wg, Rg, WhF, RT);

  // layer 0: gather+LN fused into GEMM; scan gathers residual from emb directly
  k_gemm<1><<<1024, 256, 0, stream>>>(emb, ids, ln_w, ln_b, WhF, bg, preP);
  k_scan<0><<<256, 256, 0, stream>>>(preP, RT, gn_w, emb, ids, x1,
                                     nullptr, nullptr, nullptr, nullptr, nullptr);
  // layer 1: LN fused into GEMM; head MLP fused into scan epilogue
  k_gemm<0><<<1024, 256, 0, stream>>>(x1, nullptr, ln_w + Dn, ln_b + Dn,
                                      WhF + 65536, bg + Cn, preP);
  k_scan<1><<<256, 256, 0, stream>>>(preP, RT + 16384, gn_w + Dn, x1, nullptr,
                                     nullptr, w1, b1, w2, b2, out);
}

// Round 6
// 229.283 us; speedup vs baseline: 1.1773x; 1.1773x over previous
//
#include <hip/hip_runtime.h>

typedef _Float16 f16;
typedef unsigned int uint;
typedef f16 f16x2 __attribute__((ext_vector_type(2)));
typedef f16 f16x8 __attribute__((ext_vector_type(8)));
typedef __fp16 h16x2 __attribute__((ext_vector_type(2)));
typedef float f32x4 __attribute__((ext_vector_type(4)));

#define Bn 512
#define Ln 128
#define Dn 128
#define Cn 512   // 4 gates * D

__device__ __forceinline__ float fdot2f(uint a, uint b, float c) {
#if __has_builtin(__builtin_amdgcn_fdot2)
  return __builtin_amdgcn_fdot2(__builtin_bit_cast(f16x2, a),
                                __builtin_bit_cast(f16x2, b), c, false);
#else
  f16x2 av = __builtin_bit_cast(f16x2, a), bv = __builtin_bit_cast(f16x2, b);
  return c + (float)av[0] * (float)bv[0] + (float)av[1] * (float)bv[1];
#endif
}

__device__ __forceinline__ uint pk2(float a, float b) {
#if __has_builtin(__builtin_amdgcn_cvt_pkrtz)
  h16x2 v = __builtin_amdgcn_cvt_pkrtz(a, b);
  return __builtin_bit_cast(uint, v);
#else
  f16x2 v; v[0] = (f16)a; v[1] = (f16)b;
  return __builtin_bit_cast(uint, v);
#endif
}

// DPP row_ror<N> (VALU, 2-cyc): rotational reduce within 16-lane rows.
template<int CTRL>
__device__ __forceinline__ float rorf(float x) {
#if __has_builtin(__builtin_amdgcn_mov_dpp)
  int r = __builtin_amdgcn_mov_dpp(__builtin_bit_cast(int, x), CTRL, 0xF, 0xF, true);
  return __builtin_bit_cast(float, r);
#else
  return __shfl_xor(x, (CTRL - 0x120));
#endif
}

// lane ^ 16 exchange via ds_swizzle (BitMode xor=16, and=0x1F) — LDS pipe,
// result intentionally NOT consumed at issue site (deferred to next step).
__device__ __forceinline__ int swz16i(float x) {
#if __has_builtin(__builtin_amdgcn_ds_swizzle)
  return __builtin_amdgcn_ds_swizzle(__builtin_bit_cast(int, x), 0x401F);
#else
  return __builtin_bit_cast(int, __shfl_xor(x, 16));
#endif
}

__device__ __forceinline__ void read_hu(const f16* base, uint hu[16]) {
  const uint4* hq = (const uint4*)base;
  uint4 q0 = hq[0], q1 = hq[1], q2 = hq[2], q3 = hq[3];
  hu[0]=q0.x; hu[1]=q0.y; hu[2]=q0.z; hu[3]=q0.w;
  hu[4]=q1.x; hu[5]=q1.y; hu[6]=q1.z; hu[7]=q1.w;
  hu[8]=q2.x; hu[9]=q2.y; hu[10]=q2.z; hu[11]=q2.w;
  hu[12]=q3.x; hu[13]=q3.y; hu[14]=q3.z; hu[15]=q3.w;
}

// ---------------- convert: W -> MFMA-fragment-ordered f16 (WhF), R -> transposed f16 ----------------
__global__ __launch_bounds__(256) void k_convert(const float* __restrict__ Wg,
                                                 const float* __restrict__ Rg,
                                                 f16* __restrict__ WhF,
                                                 f16* __restrict__ RT) {
  int i = blockIdx.x * 256 + threadIdx.x;
  const int nWfrag = 2 * 4 * 32 * 64;   // 16384 groups of 8 f16
  if (i < nWfrag) {
    int lane = i & 63;
    int ii   = (i >> 6) & 31;
    int kk   = (i >> 11) & 3;
    int l    = i >> 13;
    int c = ii * 16 + (lane & 15);
    int d = kk * 32 + ((lane >> 4) << 3);
    const float* src = Wg + ((size_t)(l * 512 + c) * 128 + d);
    f16* dst = WhF + (size_t)i * 8;
    #pragma unroll
    for (int j = 0; j < 8; ++j) dst[j] = (f16)src[j];
  } else {
    int j = i - nWfrag;  // 32768 = 2*4*4*32*32
    if (j < 32768) {
      int dd = j & 31;
      int e  = (j >> 5) & 31;
      int hh = (j >> 10) & 3;
      int g  = (j >> 12) & 3;
      int l  = j >> 14;
      RT[j] = (f16)Rg[((((l * 4 + g) * 4 + hh) * 32 + dd) * 32) + e];
    }
  }
}

// ---------------- GEMM, B-resident-in-registers, inline LayerNorm ----------------
// Wave w owns output cols i in {2w,2w+1}+{0,8,16,24} — exactly the 8 i-values
// its gate-packed uint2 stores need. Its 32 B-fragments (128 VGPR) are loaded
// ONCE per block, then 8 m-tiles of 16 rows stream through: A-load+LN -> 32
// MFMA (register B, no loads) -> 8 packed stores. Kills the per-MFMA L2
// dependent-load chain that left MfmaUtil at 5%.
template<int EMB>
__global__ __launch_bounds__(256, 2) void k_gemm(const float* __restrict__ xsrc,
                                                 const int* __restrict__ ids,
                                                 const float* __restrict__ lw,
                                                 const float* __restrict__ lb,
                                                 const f16* __restrict__ WhF,
                                                 const float* __restrict__ bias,
                                                 uint2* __restrict__ preP) {
  int w = threadIdx.x >> 6;
  int lane = threadIdx.x & 63;
  int l16 = lane & 15, quad = lane >> 4;

  // resident B fragments: [j][g][kk], i = 2w + j + 8g
  f16x8 bregs[2][4][4];
  #pragma unroll
  for (int j = 0; j < 2; ++j)
    #pragma unroll
    for (int g = 0; g < 4; ++g) {
      int i = 2 * w + j + 8 * g;
      #pragma unroll
      for (int kk = 0; kk < 4; ++kk)
        bregs[j][g][kk] = *(const f16x8*)(WhF + (size_t)(kk * 32 + i) * 512 + lane * 8);
    }
  float bv[2][4];
  #pragma unroll
  for (int j = 0; j < 2; ++j)
    #pragma unroll
    for (int g = 0; g < 4; ++g)
      bv[j][g] = bias[(2 * w + j + 8 * g) * 16 + l16];

  // LN weight slice for this lane (dims kk*32 + quad*8 + 0..7)
  f32x4 lw4[4][2], lb4[4][2];
  #pragma unroll
  for (int kk = 0; kk < 4; ++kk)
    #pragma unroll
    for (int p = 0; p < 2; ++p) {
      int d0 = kk * 32 + quad * 8 + p * 4;
      lw4[kk][p] = *(const f32x4*)(lw + d0);
      lb4[kk][p] = *(const f32x4*)(lb + d0);
    }

  #pragma unroll 1
  for (int t16 = 0; t16 < 8; ++t16) {
    int m0 = blockIdx.x * 128 + t16 * 16;

    const float* src;
    if (EMB) src = xsrc + (size_t)ids[m0 + l16] * Dn;
    else     src = xsrc + (size_t)(m0 + l16) * Dn;
    const float* sp = src + quad * 8;

    f32x4 v[4][2];
    #pragma unroll
    for (int kk = 0; kk < 4; ++kk) {
      v[kk][0] = *(const f32x4*)(sp + kk * 32);
      v[kk][1] = *(const f32x4*)(sp + kk * 32 + 4);
    }
    float s1 = 0.f, s2 = 0.f;
    #pragma unroll
    for (int kk = 0; kk < 4; ++kk)
      #pragma unroll
      for (int p = 0; p < 2; ++p)
        #pragma unroll
        for (int j = 0; j < 4; ++j) {
          float vv = v[kk][p][j];
          s1 += vv; s2 = fmaf(vv, vv, s2);
        }
    s1 += __shfl_xor(s1, 16);  s2 += __shfl_xor(s2, 16);
    s1 += __shfl_xor(s1, 32);  s2 += __shfl_xor(s2, 32);
    float mu = s1 * (1.f / 128.f);
    float var = s2 * (1.f / 128.f) - mu * mu;
    float rs = rsqrtf(var + 1e-5f);

    f16x8 a[4];
    #pragma unroll
    for (int kk = 0; kk < 4; ++kk)
      #pragma unroll
      for (int p = 0; p < 2; ++p)
        #pragma unroll
        for (int j = 0; j < 4; ++j)
          a[kk][p * 4 + j] = (f16)((v[kk][p][j] - mu) * rs * lw4[kk][p][j] + lb4[kk][p][j]);

    f32x4 acc[2][4] = {};
    #pragma unroll
    for (int kk = 0; kk < 4; ++kk)
      #pragma unroll
      for (int j = 0; j < 2; ++j)
        #pragma unroll
        for (int g = 0; g < 4; ++g)
          acc[j][g] = __builtin_amdgcn_mfma_f32_16x16x32_f16(a[kk], bregs[j][g][kk], acc[j][g], 0, 0, 0);

    #pragma unroll
    for (int r = 0; r < 4; ++r) {
      int m = m0 + quad * 4 + r;
      #pragma unroll
      for (int j = 0; j < 2; ++j) {
        uint2 vv;
        vv.x = pk2(acc[j][0][r] + bv[j][0], acc[j][1][r] + bv[j][1]);
        vv.y = pk2(acc[j][2][r] + bv[j][2], acc[j][3][r] + bv[j][3]);
        preP[(size_t)m * Dn + (2 * w + j) * 16 + l16] = vv;
      }
    }
  }
}

// ---------------- fused scan (r4 pipelined schedule, unchanged math) ----------------
// LAST=0 (layer 0): residual x gathered directly from emb[ids[t]] per step;
//                   writes xout = x1.
// LAST=1 (layer 1): residual from x1; mean-pool accumulated in-register; head
//                   MLP (128->64 relu ->2) computed in the epilogue via LDS.
template<int LAST>
__global__ __launch_bounds__(256, 1) void k_scan(const uint2* __restrict__ preP,
                                                 const f16* __restrict__ RT,
                                                 const float* __restrict__ gnw,
                                                 const float* __restrict__ xsrc,
                                                 const int* __restrict__ ids,
                                                 float* __restrict__ xout,
                                                 const float* __restrict__ hw1,
                                                 const float* __restrict__ hb1,
                                                 const float* __restrict__ hw2,
                                                 const float* __restrict__ hb2,
                                                 float* __restrict__ out) {
  const int w = threadIdx.x >> 6;       // wave 0..3
  const int lane = threadIdx.x & 63;
  const int s = w >> 1;                 // seq within block
  const int b = blockIdx.x * 2 + s;
  const int d = ((w & 1) << 6) + lane;  // element 0..127 of this seq
  const int head = d >> 5;
  const int e = d & 31;
  const int half = lane >> 5;

  __shared__ __align__(16) f16 hsh[4][64];   // per-wave h exchange
  __shared__ float pool2[2][128];            // LAST: pooled rows
  __shared__ float hid2[2][64];              // LAST: hidden layer

  uint rr[4][16];
  const uint* RT32 = (const uint*)RT;
  #pragma unroll
  for (int g = 0; g < 4; ++g) {
    const uint* p = RT32 + ((g * 4 + head) * 32 + e) * 16;
    #pragma unroll
    for (int j = 0; j < 16; ++j) rr[g][j] = p[j];
  }
  const float gw = gnw[d];
  const f16* hbase = &hsh[w][half * 32];   // my head-group's 32 h values

  hsh[w][lane] = (f16)0.f;   // wave-local, DS in-order

  const uint2* pp = preP + (size_t)b * Ln * Dn + d;   // + t*Dn
  const float* xp = xsrc + (size_t)b * Ln * Dn + d;   // LAST=1 residual path
  const int*   idr = ids + b * Ln;                    // LAST=0 gather path
  float* xo = xout + (size_t)b * Ln * Dn + d;

  // 4-deep prefetch pipeline (preP overrun stays inside workspace)
  uint2 pb[4]; float xb[4]; int idb[4];
  #pragma unroll
  for (int k = 0; k < 4; ++k) {
    pb[k] = pp[(size_t)k * Dn];
    if (LAST) {
      xb[k] = xp[(size_t)k * Dn];
    } else {
      xb[k] = xsrc[(size_t)idr[k] * Dn + d];
      idb[k] = idr[k + 4];
    }
  }

  // preheader: hu for t=0 (all zeros, but read keeps the pipeline uniform)
  uint hu[16];
  read_hu(hbase, hu);

  float cc = 0.f, nc = 0.f, mc = 0.f, psum = 0.f;
  float hprev = 0.f, xprev = 0.f;
  float u1 = 0.f, u2 = 0.f;   // 16-row partial GN sums of step t-1
  int   w1 = 0,   w2 = 0;     // raw ds_swizzle results (other 16-row sums)

  #pragma unroll 1
  for (int t = 0; t < Ln; t += 4) {
    #pragma unroll
    for (int k = 0; k < 4; ++k) {
      int tt = t + k;
      uint2 pc = pb[k]; float xc = xb[k];
      pb[k] = pp[(size_t)(tt + 4) * Dn];
      if (LAST) {
        xb[k] = xp[(size_t)(tt + 4) * Dn];
      } else {
        xb[k] = xsrc[(size_t)idb[k] * Dn + d];
        int ni = tt + 8;
        idb[k] = idr[ni > 127 ? 127 : ni];
      }

      // GN of step tt-1: combine deferred swizzle halves here
      if (tt > 0) {
        float s1 = u1 + __builtin_bit_cast(float, w1);
        float s2 = u2 + __builtin_bit_cast(float, w2);
        float mu = s1 * (1.f / 32.f);
        float va = s2 * (1.f / 32.f) - mu * mu;
        float ov = xprev + (hprev - mu) * rsqrtf(va + 1e-5f) * gw;
        if (LAST) psum += ov;
        else      xo[(size_t)(tt - 1) * Dn] = ov;
      }

      // recurrence dot products: 8 chains of 8 (2-way split per gate)
      float a0 = 0.f, a1 = 0.f, a2 = 0.f, a3 = 0.f;
      float c0 = 0.f, c1 = 0.f, c2 = 0.f, c3 = 0.f;
      #pragma unroll
      for (int j = 0; j < 8; ++j) {
        a0 = fdot2f(hu[j], rr[0][j], a0);
        a1 = fdot2f(hu[j], rr[1][j], a1);
        a2 = fdot2f(hu[j], rr[2][j], a2);
        a3 = fdot2f(hu[j], rr[3][j], a3);
        c0 = fdot2f(hu[j + 8], rr[0][j + 8], c0);
        c1 = fdot2f(hu[j + 8], rr[1][j + 8], c1);
        c2 = fdot2f(hu[j + 8], rr[2][j + 8], c2);
        c3 = fdot2f(hu[j + 8], rr[3][j + 8], c3);
      }
      f16x2 lo = __builtin_bit_cast(f16x2, pc.x);
      f16x2 hi = __builtin_bit_cast(f16x2, pc.y);
      float it = ((float)lo[0] + a0) + c0;
      float ft = ((float)lo[1] + a1) + c1;
      float zt = ((float)hi[0] + a2) + c2;
      float ot = ((float)hi[1] + a3) + c3;

      float mn = fmaxf(ft + mc, it);
      float iv = __expf(it - mn);
      float fv = __expf(ft + mc - mn);
      float zc = fminf(fmaxf(zt, -15.f), 15.f);
      float ez = __expf(2.f * zc);
      float tz = (ez - 1.f) * __builtin_amdgcn_rcpf(ez + 1.f);
      float cn = fv * cc + iv * tz;
      float nn = fv * nc + iv;
      // h = sigmoid(ot) * c / n = c / ((1 + exp(-ot)) * n)  — single rcp
      float hn = cn * __builtin_amdgcn_rcpf((1.f + __expf(-ot)) * nn);
      cc = cn; nc = nn; mc = mn;

      // --- DS schedule for next step (issue-only, no consumption here) ---
      hsh[w][lane] = (f16)hn;                       // DS op 1: h exchange

      float t1v = hn, t2v = hn * hn;                // VALU rors: 16-row sums
      t1v += rorf<0x121>(t1v);  t2v += rorf<0x121>(t2v);   // ror 1
      t1v += rorf<0x122>(t1v);  t2v += rorf<0x122>(t2v);   // ror 2
      t1v += rorf<0x124>(t1v);  t2v += rorf<0x124>(t2v);   // ror 4
      t1v += rorf<0x128>(t1v);  t2v += rorf<0x128>(t2v);   // ror 8
      w1 = swz16i(t1v);                             // DS ops 2,3: xor-16
      w2 = swz16i(t2v);                             //   (combined next step)
      u1 = t1v; u2 = t2v;

      read_hu(hbase, hu);                           // DS ops 4..7: hu for t+1

      hprev = hn; xprev = xc;
    }
  }

  // epilogue: groupnorm of step 127
  {
    float s1 = u1 + __builtin_bit_cast(float, w1);
    float s2 = u2 + __builtin_bit_cast(float, w2);
    float mu = s1 * (1.f / 32.f);
    float va = s2 * (1.f / 32.f) - mu * mu;
    float ov = xprev + (hprev - mu) * rsqrtf(va + 1e-5f) * gw;
    if (LAST) {
      psum += ov;
      pool2[s][d] = psum * (1.f / 128.f);
      __syncthreads();
      // head MLP: waves 0,2 handle local seqs 0,1
      if ((w & 1) == 0) {
        int sq = w >> 1;
        float acc = hb1[lane];
        const float* wr = hw1 + (size_t)lane * Dn;
        const float* pl = &pool2[sq][0];
        #pragma unroll 8
        for (int dd = 0; dd < Dn; dd += 4) {
          f32x4 wv = *(const f32x4*)(wr + dd);
          acc += wv[0]*pl[dd] + wv[1]*pl[dd+1] + wv[2]*pl[dd+2] + wv[3]*pl[dd+3];
        }
        hid2[sq][lane] = fmaxf(acc, 0.f);
      }
      __syncthreads();
      if ((w & 1) == 0 && lane < 2) {
        int sq = w >> 1;
        float acc = hb2[lane];
        const float* wr = hw2 + lane * 64;
        #pragma unroll 4
        for (int j = 0; j < 64; ++j) acc += hid2[sq][j] * wr[j];
        out[(blockIdx.x * 2 + sq) * 2 + lane] = acc;
      }
    } else {
      xo[(size_t)(Ln - 1) * Dn] = ov;
    }
  }
}

extern "C" void kernel_launch(void* const* d_in, const int* in_sizes, int n_in,
                              void* d_out, int out_size, void* d_ws, size_t ws_size,
                              hipStream_t stream) {
  const int*   ids  = (const int*)d_in[0];
  const float* emb  = (const float*)d_in[1];
  const float* ln_w = (const float*)d_in[2];
  const float* ln_b = (const float*)d_in[3];
  const float* Wg   = (const float*)d_in[4];
  const float* Rg   = (const float*)d_in[5];
  const float* bg   = (const float*)d_in[6];
  const float* gn_w = (const float*)d_in[7];
  const float* w1   = (const float*)d_in[8];
  const float* b1   = (const float*)d_in[9];
  const float* w2   = (const float*)d_in[10];
  const float* b2   = (const float*)d_in[11];
  float* out = (float*)d_out;

  char* ws = (char*)d_ws;
  uint2* preP = (uint2*)ws;                        // 67,108,864 B
  float* x1   = (float*)(ws + 67108864);           // 33,554,432 B
  f16*   WhF  = (f16*)(ws + 100663296);            //    262,144 B
  f16*   RT   = (f16*)(ws + 100663296 + 262144);   //     65,536 B

  k_convert<<<192, 256, 0, stream>>>(Wg, Rg, WhF, RT);

  // layer 0: gather+LN fused into GEMM; scan gathers residual from emb directly
  k_gemm<1><<<512, 256, 0, stream>>>(emb, ids, ln_w, ln_b, WhF, bg, preP);
  k_scan<0><<<256, 256, 0, stream>>>(preP, RT, gn_w, emb, ids, x1,
                                     nullptr, nullptr, nullptr, nullptr, nullptr);
  // layer 1: LN fused into GEMM; head MLP fused into scan epilogue
  k_gemm<0><<<512, 256, 0, stream>>>(x1, nullptr, ln_w + Dn, ln_b + Dn,
                                     WhF + 65536, bg + Cn, preP);
  k_scan<1><<<256, 256, 0, stream>>>(preP, RT + 16384, gn_w + Dn, x1, nullptr,
                                     nullptr, w1, b1, w2, b2, out);
}